// Round 1
// baseline (558.635 us; speedup 1.0000x reference)
//
#include <hip/hip_runtime.h>

typedef unsigned short u16;
typedef unsigned int u32;

typedef __attribute__((ext_vector_type(4))) float f32x4;
typedef __attribute__((ext_vector_type(8))) short bf16x8;

// ---- helpers ----------------------------------------------------------

__device__ inline u16 f2b(float f) {
  union { float f; u32 u; } x; x.f = f;
  u32 u = x.u;
  u32 r = (u + 0x7fffu + ((u >> 16) & 1u)) >> 16;   // round-nearest-even
  return (u16)r;
}

__device__ inline void gload_lds16(const void* g, void* l) {
  __builtin_amdgcn_global_load_lds(
      (const __attribute__((address_space(1))) u32*)g,
      (__attribute__((address_space(3))) u32*)l, 16, 0, 0);
}

// ---- fp32 -> bf16 convert --------------------------------------------

__global__ __launch_bounds__(256) void cvt_bf16(const float* __restrict__ src,
                                                u16* __restrict__ dst, int n4) {
  int i = blockIdx.x * blockDim.x + threadIdx.x;
  if (i >= n4) return;
  float4 v = ((const float4*)src)[i];
  ushort4 o;
  o.x = f2b(v.x); o.y = f2b(v.y); o.z = f2b(v.z); o.w = f2b(v.w);
  ((ushort4*)dst)[i] = o;
}

// ---- GEMM: out[m][n] = sum_k A[m][k] * W[n][k] + bias[n] --------------
// MODE 0: write fp32 row-major [M][N] to outF
// MODE 1: write bf16 to outB in [B=4,H=16,T=2048,D=64] layout (m=b*2048+t, n=h*64+d)

template <int MODE>
__global__ __launch_bounds__(256) void gemm_bt(const u16* __restrict__ A,
                                               const u16* __restrict__ W,
                                               const float* __restrict__ bias,
                                               float* __restrict__ outF,
                                               u16* __restrict__ outB,
                                               int M, int N, int K) {
  __shared__ u16 sA[128 * 32];
  __shared__ u16 sB[128 * 32];

  const int t = threadIdx.x;
  const int lane = t & 63;
  const int w = t >> 6;
  const int wr = w >> 1, wc = w & 1;      // 2x2 waves, each 64x64 output
  const int lr = lane & 15, lg = lane >> 4;
  const int mBase = blockIdx.y * 128;
  const int nBase = blockIdx.x * 128;

  f32x4 zero = {0.f, 0.f, 0.f, 0.f};
  f32x4 acc[4][4];
#pragma unroll
  for (int i = 0; i < 4; ++i)
#pragma unroll
    for (int j = 0; j < 4; ++j) acc[i][j] = zero;

  const int rA = t >> 2;          // tile row covered by this thread's 16B
  const int cA = (t & 3) * 8;     // k-element offset

  for (int k0 = 0; k0 < K; k0 += 32) {
#pragma unroll
    for (int i = 0; i < 2; ++i) {
      gload_lds16(A + (size_t)(mBase + i * 64 + rA) * K + k0 + cA,
                  &sA[i * 2048 + t * 8]);
      gload_lds16(W + (size_t)(nBase + i * 64 + rA) * K + k0 + cA,
                  &sB[i * 2048 + t * 8]);
    }
    __syncthreads();

    bf16x8 af[4], bf[4];
#pragma unroll
    for (int i = 0; i < 4; ++i)
      af[i] = *(const bf16x8*)&sA[(wr * 64 + i * 16 + lr) * 32 + lg * 8];
#pragma unroll
    for (int j = 0; j < 4; ++j)
      bf[j] = *(const bf16x8*)&sB[(wc * 64 + j * 16 + lr) * 32 + lg * 8];

#pragma unroll
    for (int i = 0; i < 4; ++i)
#pragma unroll
      for (int j = 0; j < 4; ++j)
        acc[i][j] = __builtin_amdgcn_mfma_f32_16x16x32_bf16(af[i], bf[j],
                                                            acc[i][j], 0, 0, 0);
    __syncthreads();
  }

  // epilogue: C/D layout col=lane&15, row=(lane>>4)*4+r
#pragma unroll
  for (int i = 0; i < 4; ++i) {
    int row = mBase + wr * 64 + i * 16 + lg * 4;
#pragma unroll
    for (int j = 0; j < 4; ++j) {
      int col = nBase + wc * 64 + j * 16 + lr;
      float bv = bias[col];
#pragma unroll
      for (int r = 0; r < 4; ++r) {
        float v = acc[i][j][r] + bv;
        if (MODE == 0) {
          outF[(size_t)(row + r) * N + col] = v;
        } else {
          int m = row + r;
          int b = m >> 11, tp = m & 2047;
          int h = col >> 6, d = col & 63;
          outB[(((size_t)(b * 16 + h) * 2048) + tp) * 64 + d] = f2b(v);
        }
      }
    }
  }
}

// ---- causal flash attention ------------------------------------------
// q,k,v: bf16 [BH=64][T=2048][D=64]; y out: bf16 [B=4][T=2048][C=1024]
// block: 256 thr (4 waves), Q tile = 64 rows (16 per wave), KV tile = 64

__global__ __launch_bounds__(256) void attn_fwd(const u16* __restrict__ qg,
                                                const u16* __restrict__ kg,
                                                const u16* __restrict__ vg,
                                                u16* __restrict__ yg) {
  __shared__ u16 sQ[64 * 72];
  __shared__ u16 sK[64 * 72];
  __shared__ u16 sVt[64 * 72];   // transposed: [d][key]
  __shared__ u16 sP[64 * 72];

  const int t = threadIdx.x;
  const int lane = t & 63;
  const int w = t >> 6;
  const int wq = w * 16;          // this wave's q-row base within tile
  const int lr = lane & 15, lg = lane >> 4;
  const int qt = blockIdx.x;
  const int bh = blockIdx.y;
  const size_t base = (size_t)bh * 2048 * 64;

  // load Q tile (bf16 pairs as u32)
  {
    const u32* qs = (const u32*)(qg + base + (size_t)qt * 64 * 64);
#pragma unroll
    for (int e = 0; e < 8; ++e) {
      int p = t + e * 256;
      int row = p >> 5, dp = p & 31;
      *(u32*)&sQ[row * 72 + dp * 2] = qs[p];
    }
  }

  f32x4 zero = {0.f, 0.f, 0.f, 0.f};
  f32x4 accO[4];
#pragma unroll
  for (int n = 0; n < 4; ++n) accO[n] = zero;
  float mrun[4] = {-1e30f, -1e30f, -1e30f, -1e30f};
  float lrun[4] = {0.f, 0.f, 0.f, 0.f};

  for (int kt = 0; kt <= qt; ++kt) {
    __syncthreads();   // previous iteration's LDS reads complete
    {
      const u32* ks = (const u32*)(kg + base + (size_t)kt * 64 * 64);
      const u32* vs = (const u32*)(vg + base + (size_t)kt * 64 * 64);
#pragma unroll
      for (int e = 0; e < 8; ++e) {
        int p = t + e * 256;
        int key = p >> 5, dp = p & 31;
        *(u32*)&sK[key * 72 + dp * 2] = ks[p];
        u32 v2 = vs[p];
        sVt[(dp * 2) * 72 + key] = (u16)(v2 & 0xffff);
        sVt[(dp * 2 + 1) * 72 + key] = (u16)(v2 >> 16);
      }
    }
    __syncthreads();

    // S = Q K^T (wave computes its 16 q-rows x 64 keys)
    bf16x8 qf[2];
#pragma unroll
    for (int kk = 0; kk < 2; ++kk)
      qf[kk] = *(const bf16x8*)&sQ[(wq + lr) * 72 + kk * 32 + lg * 8];

    f32x4 s[4];
#pragma unroll
    for (int n = 0; n < 4; ++n) {
      f32x4 a = zero;
#pragma unroll
      for (int kk = 0; kk < 2; ++kk) {
        bf16x8 kf = *(const bf16x8*)&sK[(n * 16 + lr) * 72 + kk * 32 + lg * 8];
        a = __builtin_amdgcn_mfma_f32_16x16x32_bf16(qf[kk], kf, a, 0, 0, 0);
      }
      s[n] = a;
    }

    // scale + causal mask
    const int qrow0 = qt * 64 + wq + lg * 4;
#pragma unroll
    for (int n = 0; n < 4; ++n) {
      int kcol = kt * 64 + n * 16 + lr;
#pragma unroll
      for (int r = 0; r < 4; ++r) {
        float v = s[n][r] * 0.125f;
        s[n][r] = (kcol <= qrow0 + r) ? v : -1e30f;
      }
    }

    // online softmax (rows live on 16-lane groups; reduce via shfl_xor 1,2,4,8)
#pragma unroll
    for (int r = 0; r < 4; ++r) {
      float m0 = fmaxf(fmaxf(s[0][r], s[1][r]), fmaxf(s[2][r], s[3][r]));
      m0 = fmaxf(m0, __shfl_xor(m0, 1));
      m0 = fmaxf(m0, __shfl_xor(m0, 2));
      m0 = fmaxf(m0, __shfl_xor(m0, 4));
      m0 = fmaxf(m0, __shfl_xor(m0, 8));
      float mnew = fmaxf(mrun[r], m0);
      float corr = __expf(mrun[r] - mnew);
      mrun[r] = mnew;
      float ps = 0.f;
#pragma unroll
      for (int n = 0; n < 4; ++n) {
        float p = __expf(s[n][r] - mnew);
        s[n][r] = p;
        ps += p;
      }
      ps += __shfl_xor(ps, 1);
      ps += __shfl_xor(ps, 2);
      ps += __shfl_xor(ps, 4);
      ps += __shfl_xor(ps, 8);
      lrun[r] = lrun[r] * corr + ps;
#pragma unroll
      for (int n = 0; n < 4; ++n) accO[n][r] *= corr;
    }

    // P -> LDS (bf16), re-layout C/D -> A fragments (wave-private rows)
#pragma unroll
    for (int n = 0; n < 4; ++n)
#pragma unroll
      for (int r = 0; r < 4; ++r)
        sP[(wq + lg * 4 + r) * 72 + n * 16 + lr] = f2b(s[n][r]);

    // O += P V
    bf16x8 pf[2];
#pragma unroll
    for (int kk = 0; kk < 2; ++kk)
      pf[kk] = *(const bf16x8*)&sP[(wq + lr) * 72 + kk * 32 + lg * 8];
#pragma unroll
    for (int n = 0; n < 4; ++n) {
#pragma unroll
      for (int kk = 0; kk < 2; ++kk) {
        bf16x8 vf = *(const bf16x8*)&sVt[(n * 16 + lr) * 72 + kk * 32 + lg * 8];
        accO[n] = __builtin_amdgcn_mfma_f32_16x16x32_bf16(pf[kk], vf, accO[n], 0, 0, 0);
      }
    }
  }

  // epilogue: y[b][t][h*64+d] bf16
  const int b = bh >> 4, h = bh & 15;
#pragma unroll
  for (int r = 0; r < 4; ++r) {
    int trow = qt * 64 + wq + lg * 4 + r;
    float inv = 1.f / lrun[r];
    size_t rowOff = ((size_t)b * 2048 + trow) * 1024 + h * 64;
#pragma unroll
    for (int n = 0; n < 4; ++n)
      yg[rowOff + n * 16 + lr] = f2b(accO[n][r] * inv);
  }
}

// ---- launch -----------------------------------------------------------

extern "C" void kernel_launch(void* const* d_in, const int* in_sizes, int n_in,
                              void* d_out, int out_size, void* d_ws, size_t ws_size,
                              hipStream_t stream) {
  const float* x  = (const float*)d_in[0];
  const float* Wq = (const float*)d_in[1];
  const float* bq = (const float*)d_in[2];
  const float* Wk = (const float*)d_in[3];
  const float* bk = (const float*)d_in[4];
  const float* Wv = (const float*)d_in[5];
  const float* bv = (const float*)d_in[6];
  const float* Wp = (const float*)d_in[7];
  const float* bp = (const float*)d_in[8];
  float* out = (float*)d_out;

  char* ws = (char*)d_ws;
  u16* xb  = (u16*)(ws);                      // 16 MB  [8192][1024]
  u16* wqb = (u16*)(ws + (16u << 20));        // 2 MB
  u16* wkb = (u16*)(ws + (18u << 20));
  u16* wvb = (u16*)(ws + (20u << 20));
  u16* wpb = (u16*)(ws + (22u << 20));
  u16* qb  = (u16*)(ws + (24u << 20));        // 16 MB [64][2048][64]
  u16* kb  = (u16*)(ws + (40u << 20));
  u16* vb  = (u16*)(ws + (56u << 20));
  u16* yb  = (u16*)(ws + (72u << 20));        // 16 MB [8192][1024]

  // fp32 -> bf16
  cvt_bf16<<<8192, 256, 0, stream>>>(x, xb, 2097152);
  cvt_bf16<<<1024, 256, 0, stream>>>(Wq, wqb, 262144);
  cvt_bf16<<<1024, 256, 0, stream>>>(Wk, wkb, 262144);
  cvt_bf16<<<1024, 256, 0, stream>>>(Wv, wvb, 262144);
  cvt_bf16<<<1024, 256, 0, stream>>>(Wp, wpb, 262144);

  // QKV projections -> [B,H,T,D] bf16
  gemm_bt<1><<<dim3(8, 64), 256, 0, stream>>>(xb, wqb, bq, nullptr, qb, 8192, 1024, 1024);
  gemm_bt<1><<<dim3(8, 64), 256, 0, stream>>>(xb, wkb, bk, nullptr, kb, 8192, 1024, 1024);
  gemm_bt<1><<<dim3(8, 64), 256, 0, stream>>>(xb, wvb, bv, nullptr, vb, 8192, 1024, 1024);

  // causal attention -> y bf16 [B,T,C]
  attn_fwd<<<dim3(32, 64), 256, 0, stream>>>(qb, kb, vb, yb);

  // output projection -> fp32 d_out
  gemm_bt<0><<<dim3(8, 64), 256, 0, stream>>>(yb, wpb, bp, out, nullptr, 8192, 1024, 1024);
}

// Round 2
// 454.898 us; speedup vs baseline: 1.2280x; 1.2280x over previous
//
#include <hip/hip_runtime.h>

typedef unsigned short u16;
typedef unsigned int u32;

typedef __attribute__((ext_vector_type(4))) float f32x4;
typedef __attribute__((ext_vector_type(8))) short bf16x8;

// ---- helpers ----------------------------------------------------------

__device__ inline u16 f2b(float f) {
  union { float f; u32 u; } x; x.f = f;
  u32 u = x.u;
  u32 r = (u + 0x7fffu + ((u >> 16) & 1u)) >> 16;   // round-nearest-even
  return (u16)r;
}

__device__ inline void gload_lds16(const void* g, void* l) {
  __builtin_amdgcn_global_load_lds(
      (const __attribute__((address_space(1))) u32*)g,
      (__attribute__((address_space(3))) u32*)l, 16, 0, 0);
}

// 64-u16-wide LDS row with XOR chunk swizzle: permute 16B chunks within the
// 128B row by row&7. Applied identically on write and read (involution).
__device__ inline int swz(int row, int byteInRow) {
  return row * 128 + (byteInRow ^ ((row & 7) << 4));
}

// ---- fp32 -> bf16 convert --------------------------------------------

__global__ __launch_bounds__(256) void cvt_bf16(const float* __restrict__ src,
                                                u16* __restrict__ dst, int n4) {
  int i = blockIdx.x * blockDim.x + threadIdx.x;
  if (i >= n4) return;
  float4 v = ((const float4*)src)[i];
  ushort4 o;
  o.x = f2b(v.x); o.y = f2b(v.y); o.z = f2b(v.z); o.w = f2b(v.w);
  ((ushort4*)dst)[i] = o;
}

// ---- GEMM: out[m][n] = sum_k A[m][k] * W[n][k] + bias[n] --------------
// MODE 0: write fp32 row-major [M][N] to outF
// MODE 1: write bf16 to outB in [B=4,H=16,T=2048,D=64] layout (m=b*2048+t, n=h*64+d)

template <int MODE>
__global__ __launch_bounds__(256) void gemm_bt(const u16* __restrict__ A,
                                               const u16* __restrict__ W,
                                               const float* __restrict__ bias,
                                               float* __restrict__ outF,
                                               u16* __restrict__ outB,
                                               int M, int N, int K) {
  __shared__ u16 sA[128 * 32];
  __shared__ u16 sB[128 * 32];

  const int t = threadIdx.x;
  const int lane = t & 63;
  const int w = t >> 6;
  const int wr = w >> 1, wc = w & 1;      // 2x2 waves, each 64x64 output
  const int lr = lane & 15, lg = lane >> 4;
  const int mBase = blockIdx.y * 128;
  const int nBase = blockIdx.x * 128;

  f32x4 zero = {0.f, 0.f, 0.f, 0.f};
  f32x4 acc[4][4];
#pragma unroll
  for (int i = 0; i < 4; ++i)
#pragma unroll
    for (int j = 0; j < 4; ++j) acc[i][j] = zero;

  const int rA = t >> 2;          // tile row covered by this thread's 16B
  const int cA = (t & 3) * 8;     // k-element offset

  for (int k0 = 0; k0 < K; k0 += 32) {
#pragma unroll
    for (int i = 0; i < 2; ++i) {
      gload_lds16(A + (size_t)(mBase + i * 64 + rA) * K + k0 + cA,
                  &sA[i * 2048 + t * 8]);
      gload_lds16(W + (size_t)(nBase + i * 64 + rA) * K + k0 + cA,
                  &sB[i * 2048 + t * 8]);
    }
    __syncthreads();

    bf16x8 af[4], bf[4];
#pragma unroll
    for (int i = 0; i < 4; ++i)
      af[i] = *(const bf16x8*)&sA[(wr * 64 + i * 16 + lr) * 32 + lg * 8];
#pragma unroll
    for (int j = 0; j < 4; ++j)
      bf[j] = *(const bf16x8*)&sB[(wc * 64 + j * 16 + lr) * 32 + lg * 8];

#pragma unroll
    for (int i = 0; i < 4; ++i)
#pragma unroll
      for (int j = 0; j < 4; ++j)
        acc[i][j] = __builtin_amdgcn_mfma_f32_16x16x32_bf16(af[i], bf[j],
                                                            acc[i][j], 0, 0, 0);
    __syncthreads();
  }

  // epilogue: C/D layout col=lane&15, row=(lane>>4)*4+r
#pragma unroll
  for (int i = 0; i < 4; ++i) {
    int row = mBase + wr * 64 + i * 16 + lg * 4;
#pragma unroll
    for (int j = 0; j < 4; ++j) {
      int col = nBase + wc * 64 + j * 16 + lr;
      float bv = bias[col];
#pragma unroll
      for (int r = 0; r < 4; ++r) {
        float v = acc[i][j][r] + bv;
        if (MODE == 0) {
          outF[(size_t)(row + r) * N + col] = v;
        } else {
          int m = row + r;
          int b = m >> 11, tp = m & 2047;
          int h = col >> 6, d = col & 63;
          outB[(((size_t)(b * 16 + h) * 2048) + tp) * 64 + d] = f2b(v);
        }
      }
    }
  }
}

// ---- causal flash attention ------------------------------------------
// q,k,v: bf16 [BH=64][T=2048][D=64]; y out: bf16 [B=4][T=2048][C=1024]
// block: 256 thr (4 waves), Q tile = 64 rows (16 per wave), KV tile = 64
// Pipeline: prefetch next K/V tile into regs during compute (T14).
// LDS: 64-wide rows + XOR chunk swizzle (conflict-free staging + b128 reads).

__global__ __launch_bounds__(256) void attn_fwd(const u16* __restrict__ qg,
                                                const u16* __restrict__ kg,
                                                const u16* __restrict__ vg,
                                                u16* __restrict__ yg) {
  __shared__ u16 sQ[64 * 64];
  __shared__ u16 sK[64 * 64];
  __shared__ u16 sVt[64 * 64];   // transposed: [d][key]
  __shared__ u16 sP[64 * 64];

  const int t = threadIdx.x;
  const int lane = t & 63;
  const int w = t >> 6;
  const int wq = w * 16;          // this wave's q-row base within tile
  const int lr = lane & 15, lg = lane >> 4;
  const int qt = (int)gridDim.x - 1 - (int)blockIdx.x;  // long blocks first
  const int bh = blockIdx.y;
  const size_t base = (size_t)bh * 2048 * 64;

  // stage Q tile (swizzled)
  {
    const u32* qs = (const u32*)(qg + base + (size_t)qt * 64 * 64);
#pragma unroll
    for (int e = 0; e < 8; ++e) {
      int p = t + e * 256;
      int row = p >> 5, dp = p & 31;
      *(u32*)((char*)sQ + swz(row, dp * 4)) = qs[p];
    }
  }
  __syncthreads();

  // Q fragments are loop-invariant: hoist
  bf16x8 qf[2];
#pragma unroll
  for (int kk = 0; kk < 2; ++kk)
    qf[kk] = *(const bf16x8*)((const char*)sQ + swz(wq + lr, kk * 64 + lg * 16));

  f32x4 zero = {0.f, 0.f, 0.f, 0.f};
  f32x4 accO[4];
#pragma unroll
  for (int n = 0; n < 4; ++n) accO[n] = zero;
  float mrun[4] = {-1e30f, -1e30f, -1e30f, -1e30f};
  float lrun[4] = {0.f, 0.f, 0.f, 0.f};

  const u32* ks = (const u32*)(kg + base);
  const u32* vs = (const u32*)(vg + base);

  // prefetch tile 0 into registers
  u32 kreg[8], vreg[8];
#pragma unroll
  for (int e = 0; e < 8; ++e) {
    int p = t + e * 256;
    kreg[e] = ks[p];
    vreg[e] = vs[p];
  }

  for (int kt = 0; kt <= qt; ++kt) {
    __syncthreads();   // previous iteration's LDS reads complete
    // write staged tile: K row-major (swizzled), V transposed (swizzled)
#pragma unroll
    for (int e = 0; e < 8; ++e) {
      int p = t + e * 256;
      int row = p >> 5, dp = p & 31;
      *(u32*)((char*)sK + swz(row, dp * 4)) = kreg[e];
      u32 v2 = vreg[e];
      *(u16*)((char*)sVt + swz(2 * dp, row * 2)) = (u16)(v2 & 0xffff);
      *(u16*)((char*)sVt + swz(2 * dp + 1, row * 2)) = (u16)(v2 >> 16);
    }
    __syncthreads();

    // issue next tile's global loads now; they complete during compute
    if (kt < qt) {
      const u32* ksn = ks + (size_t)(kt + 1) * 2048;
      const u32* vsn = vs + (size_t)(kt + 1) * 2048;
#pragma unroll
      for (int e = 0; e < 8; ++e) {
        int p = t + e * 256;
        kreg[e] = ksn[p];
        vreg[e] = vsn[p];
      }
    }

    // S = Q K^T (wave computes its 16 q-rows x 64 keys)
    f32x4 s[4];
#pragma unroll
    for (int n = 0; n < 4; ++n) {
      f32x4 a = zero;
#pragma unroll
      for (int kk = 0; kk < 2; ++kk) {
        bf16x8 kf = *(const bf16x8*)((const char*)sK +
                                     swz(n * 16 + lr, kk * 64 + lg * 16));
        a = __builtin_amdgcn_mfma_f32_16x16x32_bf16(qf[kk], kf, a, 0, 0, 0);
      }
      s[n] = a;
    }

    // scale + causal mask
    const int qrow0 = qt * 64 + wq + lg * 4;
#pragma unroll
    for (int n = 0; n < 4; ++n) {
      int kcol = kt * 64 + n * 16 + lr;
#pragma unroll
      for (int r = 0; r < 4; ++r) {
        float v = s[n][r] * 0.125f;
        s[n][r] = (kcol <= qrow0 + r) ? v : -1e30f;
      }
    }

    // online softmax (rows live on 16-lane groups; reduce via shfl_xor 1,2,4,8)
#pragma unroll
    for (int r = 0; r < 4; ++r) {
      float m0 = fmaxf(fmaxf(s[0][r], s[1][r]), fmaxf(s[2][r], s[3][r]));
      m0 = fmaxf(m0, __shfl_xor(m0, 1));
      m0 = fmaxf(m0, __shfl_xor(m0, 2));
      m0 = fmaxf(m0, __shfl_xor(m0, 4));
      m0 = fmaxf(m0, __shfl_xor(m0, 8));
      float mnew = fmaxf(mrun[r], m0);
      float corr = __expf(mrun[r] - mnew);
      mrun[r] = mnew;
      float ps = 0.f;
#pragma unroll
      for (int n = 0; n < 4; ++n) {
        float p = __expf(s[n][r] - mnew);
        s[n][r] = p;
        ps += p;
      }
      ps += __shfl_xor(ps, 1);
      ps += __shfl_xor(ps, 2);
      ps += __shfl_xor(ps, 4);
      ps += __shfl_xor(ps, 8);
      lrun[r] = lrun[r] * corr + ps;
#pragma unroll
      for (int n = 0; n < 4; ++n) accO[n][r] *= corr;
    }

    // P -> LDS (bf16), re-layout C/D -> A fragments (wave-private rows)
#pragma unroll
    for (int n = 0; n < 4; ++n)
#pragma unroll
      for (int r = 0; r < 4; ++r)
        *(u16*)((char*)sP + swz(wq + lg * 4 + r, (n * 16 + lr) * 2)) =
            f2b(s[n][r]);

    // O += P V
    bf16x8 pf[2];
#pragma unroll
    for (int kk = 0; kk < 2; ++kk)
      pf[kk] = *(const bf16x8*)((const char*)sP +
                                swz(wq + lr, kk * 64 + lg * 16));
#pragma unroll
    for (int n = 0; n < 4; ++n) {
#pragma unroll
      for (int kk = 0; kk < 2; ++kk) {
        bf16x8 vf = *(const bf16x8*)((const char*)sVt +
                                     swz(n * 16 + lr, kk * 64 + lg * 16));
        accO[n] = __builtin_amdgcn_mfma_f32_16x16x32_bf16(pf[kk], vf, accO[n], 0, 0, 0);
      }
    }
  }

  // epilogue: y[b][t][h*64+d] bf16
  const int b = bh >> 4, h = bh & 15;
#pragma unroll
  for (int r = 0; r < 4; ++r) {
    int trow = qt * 64 + wq + lg * 4 + r;
    float inv = 1.f / lrun[r];
    size_t rowOff = ((size_t)b * 2048 + trow) * 1024 + h * 64;
#pragma unroll
    for (int n = 0; n < 4; ++n)
      yg[rowOff + n * 16 + lr] = f2b(accO[n][r] * inv);
  }
}

// ---- launch -----------------------------------------------------------

extern "C" void kernel_launch(void* const* d_in, const int* in_sizes, int n_in,
                              void* d_out, int out_size, void* d_ws, size_t ws_size,
                              hipStream_t stream) {
  const float* x  = (const float*)d_in[0];
  const float* Wq = (const float*)d_in[1];
  const float* bq = (const float*)d_in[2];
  const float* Wk = (const float*)d_in[3];
  const float* bk = (const float*)d_in[4];
  const float* Wv = (const float*)d_in[5];
  const float* bv = (const float*)d_in[6];
  const float* Wp = (const float*)d_in[7];
  const float* bp = (const float*)d_in[8];
  float* out = (float*)d_out;

  char* ws = (char*)d_ws;
  u16* xb  = (u16*)(ws);                      // 16 MB  [8192][1024]
  u16* wqb = (u16*)(ws + (16u << 20));        // 2 MB
  u16* wkb = (u16*)(ws + (18u << 20));
  u16* wvb = (u16*)(ws + (20u << 20));
  u16* wpb = (u16*)(ws + (22u << 20));
  u16* qb  = (u16*)(ws + (24u << 20));        // 16 MB [64][2048][64]
  u16* kb  = (u16*)(ws + (40u << 20));
  u16* vb  = (u16*)(ws + (56u << 20));
  u16* yb  = (u16*)(ws + (72u << 20));        // 16 MB [8192][1024]

  // fp32 -> bf16
  cvt_bf16<<<8192, 256, 0, stream>>>(x, xb, 2097152);
  cvt_bf16<<<1024, 256, 0, stream>>>(Wq, wqb, 262144);
  cvt_bf16<<<1024, 256, 0, stream>>>(Wk, wkb, 262144);
  cvt_bf16<<<1024, 256, 0, stream>>>(Wv, wvb, 262144);
  cvt_bf16<<<1024, 256, 0, stream>>>(Wp, wpb, 262144);

  // QKV projections -> [B,H,T,D] bf16
  gemm_bt<1><<<dim3(8, 64), 256, 0, stream>>>(xb, wqb, bq, nullptr, qb, 8192, 1024, 1024);
  gemm_bt<1><<<dim3(8, 64), 256, 0, stream>>>(xb, wkb, bk, nullptr, kb, 8192, 1024, 1024);
  gemm_bt<1><<<dim3(8, 64), 256, 0, stream>>>(xb, wvb, bv, nullptr, vb, 8192, 1024, 1024);

  // causal attention -> y bf16 [B,T,C]
  attn_fwd<<<dim3(32, 64), 256, 0, stream>>>(qb, kb, vb, yb);

  // output projection -> fp32 d_out
  gemm_bt<0><<<dim3(8, 64), 256, 0, stream>>>(yb, wpb, bp, out, nullptr, 8192, 1024, 1024);
}

// Round 3
// 313.471 us; speedup vs baseline: 1.7821x; 1.4512x over previous
//
#include <hip/hip_runtime.h>

typedef unsigned short u16;
typedef unsigned int u32;

typedef __attribute__((ext_vector_type(4))) float f32x4;
typedef __attribute__((ext_vector_type(8))) short bf16x8;

// ---- helpers ----------------------------------------------------------

__device__ inline u16 f2b(float f) {
  union { float f; u32 u; } x; x.f = f;
  u32 u = x.u;
  u32 r = (u + 0x7fffu + ((u >> 16) & 1u)) >> 16;   // round-nearest-even
  return (u16)r;
}

__device__ inline void gload_lds16(const void* g, void* l) {
  __builtin_amdgcn_global_load_lds(
      (const __attribute__((address_space(1))) u32*)g,
      (__attribute__((address_space(3))) u32*)l, 16, 0, 0);
}

// ---- fp32 -> bf16 convert --------------------------------------------

__global__ __launch_bounds__(256) void cvt_bf16(const float* __restrict__ src,
                                                u16* __restrict__ dst, int n4) {
  int i = blockIdx.x * blockDim.x + threadIdx.x;
  if (i >= n4) return;
  float4 v = ((const float4*)src)[i];
  ushort4 o;
  o.x = f2b(v.x); o.y = f2b(v.y); o.z = f2b(v.z); o.w = f2b(v.w);
  ((ushort4*)dst)[i] = o;
}

// ---- GEMM: out[m][n] = sum_k A[m][k] * W[n][k] + bias[n] --------------
// MODE 0: write fp32 row-major [M][N] to outF
// MODE 1: write bf16 to outB in [B=4,H=16,T=2048,D=64] layout (m=b*2048+t, n=h*64+d)

template <int MODE>
__global__ __launch_bounds__(256) void gemm_bt(const u16* __restrict__ A,
                                               const u16* __restrict__ W,
                                               const float* __restrict__ bias,
                                               float* __restrict__ outF,
                                               u16* __restrict__ outB,
                                               int M, int N, int K) {
  __shared__ u16 sA[128 * 32];
  __shared__ u16 sB[128 * 32];

  const int t = threadIdx.x;
  const int lane = t & 63;
  const int w = t >> 6;
  const int wr = w >> 1, wc = w & 1;      // 2x2 waves, each 64x64 output
  const int lr = lane & 15, lg = lane >> 4;
  const int mBase = blockIdx.y * 128;
  const int nBase = blockIdx.x * 128;

  f32x4 zero = {0.f, 0.f, 0.f, 0.f};
  f32x4 acc[4][4];
#pragma unroll
  for (int i = 0; i < 4; ++i)
#pragma unroll
    for (int j = 0; j < 4; ++j) acc[i][j] = zero;

  const int rA = t >> 2;          // tile row covered by this thread's 16B
  const int cA = (t & 3) * 8;     // k-element offset

  for (int k0 = 0; k0 < K; k0 += 32) {
#pragma unroll
    for (int i = 0; i < 2; ++i) {
      gload_lds16(A + (size_t)(mBase + i * 64 + rA) * K + k0 + cA,
                  &sA[i * 2048 + t * 8]);
      gload_lds16(W + (size_t)(nBase + i * 64 + rA) * K + k0 + cA,
                  &sB[i * 2048 + t * 8]);
    }
    __syncthreads();

    bf16x8 af[4], bf[4];
#pragma unroll
    for (int i = 0; i < 4; ++i)
      af[i] = *(const bf16x8*)&sA[(wr * 64 + i * 16 + lr) * 32 + lg * 8];
#pragma unroll
    for (int j = 0; j < 4; ++j)
      bf[j] = *(const bf16x8*)&sB[(wc * 64 + j * 16 + lr) * 32 + lg * 8];

#pragma unroll
    for (int i = 0; i < 4; ++i)
#pragma unroll
      for (int j = 0; j < 4; ++j)
        acc[i][j] = __builtin_amdgcn_mfma_f32_16x16x32_bf16(af[i], bf[j],
                                                            acc[i][j], 0, 0, 0);
    __syncthreads();
  }

  // epilogue: C/D layout col=lane&15, row=(lane>>4)*4+r
#pragma unroll
  for (int i = 0; i < 4; ++i) {
    int row = mBase + wr * 64 + i * 16 + lg * 4;
#pragma unroll
    for (int j = 0; j < 4; ++j) {
      int col = nBase + wc * 64 + j * 16 + lr;
      float bv = bias[col];
#pragma unroll
      for (int r = 0; r < 4; ++r) {
        float v = acc[i][j][r] + bv;
        if (MODE == 0) {
          outF[(size_t)(row + r) * N + col] = v;
        } else {
          int m = row + r;
          int b = m >> 11, tp = m & 2047;
          int h = col >> 6, d = col & 63;
          outB[(((size_t)(b * 16 + h) * 2048) + tp) * 64 + d] = f2b(v);
        }
      }
    }
  }
}

// ---- causal flash attention ------------------------------------------
// q,k,v: bf16 [BH=64][T=2048][D=64]; y out: bf16 [B=4][T=2048][C=1024]
// 512 thr (8 waves). Q tile = 128 rows (16 per wave), KV tile = 64.
// Swapped QK^T: S^T = mfma(K, Q) so each lane holds 16 P-values of ONE
// q-row (q = lane&15) -> softmax is lane-local + 2 shfls.
// PV non-swapped via wave-private P round-trip in LDS.

__global__ __launch_bounds__(512) void attn_fwd(const u16* __restrict__ qg,
                                                const u16* __restrict__ kg,
                                                const u16* __restrict__ vg,
                                                u16* __restrict__ yg) {
  __shared__ u16 sK[64 * 64];    // [key][d], XOR-chunk swizzled by key&7
  __shared__ u16 sVt[64 * 64];   // [d][key], XOR-chunk swizzled by (d>>1)&7
  __shared__ u16 sP[8 * 16 * 64];  // per-wave [16 q][64 key], swizzled by q&7

  const int t = threadIdx.x;
  const int lane = t & 63;
  const int w = t >> 6;
  const int lr = lane & 15, lg = lane >> 4;
  const int qt = (int)gridDim.x - 1 - (int)blockIdx.x;  // long blocks first
  const int bh = blockIdx.y;
  const size_t base = (size_t)bh * 2048 * 64;

  // Q B-fragments straight from global (col=q=lane&15, k=d slice)
  const int qrow = qt * 128 + w * 16 + lr;
  bf16x8 qf[2];
#pragma unroll
  for (int kk = 0; kk < 2; ++kk)
    qf[kk] = *(const bf16x8*)(qg + base + (size_t)qrow * 64 + kk * 32 + lg * 8);

  f32x4 zero = {0.f, 0.f, 0.f, 0.f};
  f32x4 accO[4];
#pragma unroll
  for (int n = 0; n < 4; ++n) accO[n] = zero;
  float mrun = -1e30f, lrun = 0.f;

  const u32* ks = (const u32*)(kg + base);
  const u32* vs = (const u32*)(vg + base);

  // prefetch tile 0 (4 u32 K + 4 u32 V per thread; 512 thr cover 64x64)
  u32 kreg[4], vreg[4];
#pragma unroll
  for (int e = 0; e < 4; ++e) {
    int p = t + e * 512;
    kreg[e] = ks[p];
    vreg[e] = vs[p];
  }

  char* pw = (char*)sP + w * 2048;   // wave-private 16x64 P buffer

  const int nkt = 2 * qt + 2;
  for (int kt = 0; kt < nkt; ++kt) {
    __syncthreads();   // prev iteration's LDS reads complete
#pragma unroll
    for (int e = 0; e < 4; ++e) {
      int p = t + e * 512;
      int row = p >> 5, dp = p & 31;     // row = key index, dp = d-pair
      *(u32*)((char*)sK + row * 128 + ((dp * 4) ^ ((row & 7) << 4))) = kreg[e];
      u32 v2 = vreg[e];
      int xo = (row * 2) ^ ((dp & 7) << 4);
      *(u16*)((char*)sVt + (2 * dp) * 128 + xo) = (u16)(v2 & 0xffff);
      *(u16*)((char*)sVt + (2 * dp + 1) * 128 + xo) = (u16)(v2 >> 16);
    }
    __syncthreads();

    // prefetch next tile during compute
    if (kt + 1 < nkt) {
      const u32* kn = ks + (size_t)(kt + 1) * 2048;
      const u32* vn = vs + (size_t)(kt + 1) * 2048;
#pragma unroll
      for (int e = 0; e < 4; ++e) {
        int p = t + e * 512;
        kreg[e] = kn[p];
        vreg[e] = vn[p];
      }
    }

    // S^T = K Q^T : A = K rows (keys), B = Q cols. col=lane&15 -> q = qrow.
    f32x4 s[4];
#pragma unroll
    for (int n = 0; n < 4; ++n) {
      f32x4 a = zero;
#pragma unroll
      for (int kk = 0; kk < 2; ++kk) {
        bf16x8 kf = *(const bf16x8*)((const char*)sK + (n * 16 + lr) * 128 +
                                     ((kk * 64 + lg * 16) ^ ((lr & 7) << 4)));
        a = __builtin_amdgcn_mfma_f32_16x16x32_bf16(kf, qf[kk], a, 0, 0, 0);
      }
      s[n] = a;
    }

    // mask + scale: this lane's 16 values all belong to q-row `qrow`,
    // keys = kt*64 + n*16 + lg*4 + r
#pragma unroll
    for (int n = 0; n < 4; ++n) {
      int key0 = kt * 64 + n * 16 + lg * 4;
#pragma unroll
      for (int r = 0; r < 4; ++r) {
        float v = s[n][r] * 0.125f;
        s[n][r] = (key0 + r <= qrow) ? v : -1e30f;
      }
    }

    // softmax: lane-local over 16 values, then combine lg groups (2 shfls)
    float pmax = -1e30f;
#pragma unroll
    for (int n = 0; n < 4; ++n)
      pmax = fmaxf(pmax, fmaxf(fmaxf(s[n][0], s[n][1]), fmaxf(s[n][2], s[n][3])));
    pmax = fmaxf(pmax, __shfl_xor(pmax, 16));
    pmax = fmaxf(pmax, __shfl_xor(pmax, 32));
    float mnew = fmaxf(mrun, pmax);
    float corr = __expf(mrun - mnew);
    mrun = mnew;
    float psum = 0.f;
#pragma unroll
    for (int n = 0; n < 4; ++n)
#pragma unroll
      for (int r = 0; r < 4; ++r) {
        float p = __expf(s[n][r] - mnew);
        s[n][r] = p;
        psum += p;
      }
    psum += __shfl_xor(psum, 16);
    psum += __shfl_xor(psum, 32);
    lrun = lrun * corr + psum;

    // P -> wave-private LDS (packed u32 pairs), row q=lr, col key
#pragma unroll
    for (int n = 0; n < 4; ++n)
#pragma unroll
      for (int rp = 0; rp < 4; rp += 2) {
        u32 pk = (u32)f2b(s[n][rp]) | ((u32)f2b(s[n][rp + 1]) << 16);
        *(u32*)(pw + lr * 128 +
                ((n * 32 + lg * 8 + rp * 2) ^ ((lr & 7) << 4))) = pk;
      }

    // rescale accO: its rows are q = lg*4+r -> fetch corr via 4 shfls
    float c4[4];
#pragma unroll
    for (int r = 0; r < 4; ++r) c4[r] = __shfl(corr, lg * 4 + r);
#pragma unroll
    for (int n = 0; n < 4; ++n)
#pragma unroll
      for (int r = 0; r < 4; ++r) accO[n][r] *= c4[r];

    // O += P V : A = P (row=q), B = V^T (col=d)
    bf16x8 pf[2];
#pragma unroll
    for (int kk = 0; kk < 2; ++kk)
      pf[kk] = *(const bf16x8*)(pw + lr * 128 +
                                ((kk * 64 + lg * 16) ^ ((lr & 7) << 4)));
#pragma unroll
    for (int n = 0; n < 4; ++n) {
      int drow = n * 16 + lr;
#pragma unroll
      for (int kk = 0; kk < 2; ++kk) {
        bf16x8 vf = *(const bf16x8*)((const char*)sVt + drow * 128 +
                                     ((kk * 64 + lg * 16) ^
                                      (((drow >> 1) & 7) << 4)));
        accO[n] = __builtin_amdgcn_mfma_f32_16x16x32_bf16(pf[kk], vf, accO[n], 0, 0, 0);
      }
    }
  }

  // epilogue: accO rows q = lg*4+r; lrun lives at lane lr==q -> 4 shfls
  const int b = bh >> 4, h = bh & 15;
#pragma unroll
  for (int r = 0; r < 4; ++r) {
    float linv = 1.f / __shfl(lrun, lg * 4 + r);
    int trow = qt * 128 + w * 16 + lg * 4 + r;
    size_t rowOff = ((size_t)b * 2048 + trow) * 1024 + h * 64;
#pragma unroll
    for (int n = 0; n < 4; ++n)
      yg[rowOff + n * 16 + lr] = f2b(accO[n][r] * linv);
  }
}

// ---- launch -----------------------------------------------------------

extern "C" void kernel_launch(void* const* d_in, const int* in_sizes, int n_in,
                              void* d_out, int out_size, void* d_ws, size_t ws_size,
                              hipStream_t stream) {
  const float* x  = (const float*)d_in[0];
  const float* Wq = (const float*)d_in[1];
  const float* bq = (const float*)d_in[2];
  const float* Wk = (const float*)d_in[3];
  const float* bk = (const float*)d_in[4];
  const float* Wv = (const float*)d_in[5];
  const float* bv = (const float*)d_in[6];
  const float* Wp = (const float*)d_in[7];
  const float* bp = (const float*)d_in[8];
  float* out = (float*)d_out;

  char* ws = (char*)d_ws;
  u16* xb  = (u16*)(ws);                      // 16 MB  [8192][1024]
  u16* wqb = (u16*)(ws + (16u << 20));        // 2 MB
  u16* wkb = (u16*)(ws + (18u << 20));
  u16* wvb = (u16*)(ws + (20u << 20));
  u16* wpb = (u16*)(ws + (22u << 20));
  u16* qb  = (u16*)(ws + (24u << 20));        // 16 MB [64][2048][64]
  u16* kb  = (u16*)(ws + (40u << 20));
  u16* vb  = (u16*)(ws + (56u << 20));
  u16* yb  = (u16*)(ws + (72u << 20));        // 16 MB [8192][1024]

  // fp32 -> bf16
  cvt_bf16<<<8192, 256, 0, stream>>>(x, xb, 2097152);
  cvt_bf16<<<1024, 256, 0, stream>>>(Wq, wqb, 262144);
  cvt_bf16<<<1024, 256, 0, stream>>>(Wk, wkb, 262144);
  cvt_bf16<<<1024, 256, 0, stream>>>(Wv, wvb, 262144);
  cvt_bf16<<<1024, 256, 0, stream>>>(Wp, wpb, 262144);

  // QKV projections -> [B,H,T,D] bf16
  gemm_bt<1><<<dim3(8, 64), 256, 0, stream>>>(xb, wqb, bq, nullptr, qb, 8192, 1024, 1024);
  gemm_bt<1><<<dim3(8, 64), 256, 0, stream>>>(xb, wkb, bk, nullptr, kb, 8192, 1024, 1024);
  gemm_bt<1><<<dim3(8, 64), 256, 0, stream>>>(xb, wvb, bv, nullptr, vb, 8192, 1024, 1024);

  // causal attention -> y bf16 [B,T,C]
  attn_fwd<<<dim3(16, 64), 512, 0, stream>>>(qb, kb, vb, yb);

  // output projection -> fp32 d_out
  gemm_bt<0><<<dim3(8, 64), 256, 0, stream>>>(yb, wpb, bp, out, nullptr, 8192, 1024, 1024);
}

// Round 4
// 251.152 us; speedup vs baseline: 2.2243x; 1.2481x over previous
//
#include <hip/hip_runtime.h>

typedef unsigned short u16;
typedef unsigned int u32;

typedef __attribute__((ext_vector_type(4))) float f32x4;
typedef __attribute__((ext_vector_type(8))) short bf16x8;

// ---- helpers ----------------------------------------------------------

__device__ inline u16 f2b(float f) {
  union { float f; u32 u; } x; x.f = f;
  u32 u = x.u;
  u32 r = (u + 0x7fffu + ((u >> 16) & 1u)) >> 16;   // round-nearest-even
  return (u16)r;
}

__device__ inline u32 cvtpk(float lo, float hi) {
  u32 r;
  asm("v_cvt_pk_bf16_f32 %0, %1, %2" : "=v"(r) : "v"(lo), "v"(hi));
  return r;
}

__device__ inline void gload_lds16(const void* g, void* l) {
  __builtin_amdgcn_global_load_lds(
      (const __attribute__((address_space(1))) u32*)g,
      (__attribute__((address_space(3))) u32*)l, 16, 0, 0);
}

// ---- fp32 -> bf16 convert --------------------------------------------

__global__ __launch_bounds__(256) void cvt_bf16(const float* __restrict__ src,
                                                u16* __restrict__ dst, int n4) {
  int i = blockIdx.x * blockDim.x + threadIdx.x;
  if (i >= n4) return;
  float4 v = ((const float4*)src)[i];
  ushort4 o;
  o.x = f2b(v.x); o.y = f2b(v.y); o.z = f2b(v.z); o.w = f2b(v.w);
  ((ushort4*)dst)[i] = o;
}

// merged convert for the 4 weight matrices (1024 blocks each)
__global__ __launch_bounds__(256) void cvt_w4(const float* __restrict__ w0,
                                              const float* __restrict__ w1,
                                              const float* __restrict__ w2,
                                              const float* __restrict__ w3,
                                              u16* o0, u16* o1, u16* o2, u16* o3) {
  int m = blockIdx.x >> 10;
  const float* s = (m == 0) ? w0 : (m == 1) ? w1 : (m == 2) ? w2 : w3;
  u16* d = (m == 0) ? o0 : (m == 1) ? o1 : (m == 2) ? o2 : o3;
  int i = (blockIdx.x & 1023) * 256 + threadIdx.x;
  float4 v = ((const float4*)s)[i];
  ushort4 o;
  o.x = f2b(v.x); o.y = f2b(v.y); o.z = f2b(v.z); o.w = f2b(v.w);
  ((ushort4*)d)[i] = o;
}

// ---- GEMM: out[m][n] = sum_k A[m][k] * W[n][k] + bias[n] --------------
// MODE 0: fp32 row-major [M][N] -> outF
// MODE 1: bf16 [B=4,H=16,T=2048,D=64]  (m=b*2048+t, n=h*64+d)
// MODE 2: bf16 V^T [BH=64][D=64][T=2048] (packed ushort4 along t)
// grid must be (8, 64); XCD-chunked swizzle assumes gridDim.x == 8.

template <int MODE>
__global__ __launch_bounds__(256) void gemm_bt(const u16* __restrict__ A,
                                               const u16* __restrict__ W,
                                               const float* __restrict__ bias,
                                               float* __restrict__ outF,
                                               u16* __restrict__ outB,
                                               int M, int N, int K) {
  __shared__ u16 sA[128 * 32];
  __shared__ u16 sB[128 * 32];

  const int t = threadIdx.x;
  const int lane = t & 63;
  const int w = t >> 6;
  const int wr = w >> 1, wc = w & 1;      // 2x2 waves, each 64x64 output
  const int lr = lane & 15, lg = lane >> 4;

  // XCD-chunked swizzle: each XCD gets 8 consecutive m-panels (A-panel L2 reuse)
  int bid = blockIdx.y * 8 + blockIdx.x;
  int swz = (bid & 7) * 64 + (bid >> 3);
  const int mBase = (swz >> 3) * 128;
  const int nBase = (swz & 7) * 128;

  f32x4 zero = {0.f, 0.f, 0.f, 0.f};
  f32x4 acc[4][4];
#pragma unroll
  for (int i = 0; i < 4; ++i)
#pragma unroll
    for (int j = 0; j < 4; ++j) acc[i][j] = zero;

  const int rA = t >> 2;          // tile row covered by this thread's 16B
  const int cA = (t & 3) * 8;     // k-element offset

  for (int k0 = 0; k0 < K; k0 += 32) {
#pragma unroll
    for (int i = 0; i < 2; ++i) {
      gload_lds16(A + (size_t)(mBase + i * 64 + rA) * K + k0 + cA,
                  &sA[i * 2048 + t * 8]);
      gload_lds16(W + (size_t)(nBase + i * 64 + rA) * K + k0 + cA,
                  &sB[i * 2048 + t * 8]);
    }
    __syncthreads();

    bf16x8 af[4], bf[4];
#pragma unroll
    for (int i = 0; i < 4; ++i)
      af[i] = *(const bf16x8*)&sA[(wr * 64 + i * 16 + lr) * 32 + lg * 8];
#pragma unroll
    for (int j = 0; j < 4; ++j)
      bf[j] = *(const bf16x8*)&sB[(wc * 64 + j * 16 + lr) * 32 + lg * 8];

#pragma unroll
    for (int i = 0; i < 4; ++i)
#pragma unroll
      for (int j = 0; j < 4; ++j)
        acc[i][j] = __builtin_amdgcn_mfma_f32_16x16x32_bf16(af[i], bf[j],
                                                            acc[i][j], 0, 0, 0);
    __syncthreads();
  }

  // epilogue: C/D layout col=lane&15, row=(lane>>4)*4+r
#pragma unroll
  for (int i = 0; i < 4; ++i) {
    int row = mBase + wr * 64 + i * 16 + lg * 4;   // row % 4 == 0
#pragma unroll
    for (int j = 0; j < 4; ++j) {
      int col = nBase + wc * 64 + j * 16 + lr;
      float bv = bias[col];
      if (MODE == 2) {
        // V^T: [bh][d][t], 4 consecutive t packed
        int b = row >> 11, tp = row & 2047;
        int h = col >> 6, d = col & 63;
        ushort4 o;
        o.x = f2b(acc[i][j][0] + bv);
        o.y = f2b(acc[i][j][1] + bv);
        o.z = f2b(acc[i][j][2] + bv);
        o.w = f2b(acc[i][j][3] + bv);
        *(ushort4*)(outB + ((size_t)((b * 16 + h) * 64 + d)) * 2048 + tp) = o;
      } else {
#pragma unroll
        for (int r = 0; r < 4; ++r) {
          float v = acc[i][j][r] + bv;
          if (MODE == 0) {
            outF[(size_t)(row + r) * N + col] = v;
          } else {
            int m = row + r;
            int b = m >> 11, tp = m & 2047;
            int h = col >> 6, d = col & 63;
            outB[(((size_t)(b * 16 + h) * 2048) + tp) * 64 + d] = f2b(v);
          }
        }
      }
    }
  }
}

// ---- causal flash attention ------------------------------------------
// q,k: bf16 [BH=64][T=2048][D=64]; vt: bf16 [BH=64][D=64][T=2048]
// y out: bf16 [B=4][T=2048][C=1024]
// 512 thr (8 waves). Q tile = 128 rows (16/wave), KV tile = 64.
// Swapped QK^T (S^T = mfma(K,Q)) -> lane-local softmax (q = lane&15).
// P kept in registers: cvt_pk + 8 shfl rounds build PV A-fragments.
// K and V^T staged identically (conflict-free u32 row writes, XOR chunk swz).
// Double-buffered LDS: ONE barrier per KV tile.

__global__ __launch_bounds__(512) void attn_fwd(const u16* __restrict__ qg,
                                                const u16* __restrict__ kg,
                                                const u16* __restrict__ vtg,
                                                u16* __restrict__ yg) {
  __shared__ u16 sK[2][64 * 64];
  __shared__ u16 sVt[2][64 * 64];

  const int t = threadIdx.x;
  const int lane = t & 63;
  const int w = t >> 6;
  const int lr = lane & 15, lg = lane >> 4;

  // XCD-chunked swizzle: XCD x gets bh in [8x, 8x+8), qt descending (long first)
  int bid0 = blockIdx.y * 16 + blockIdx.x;
  int swzb = (bid0 & 7) * 128 + (bid0 >> 3);
  const int bh = swzb >> 4;
  const int qt = 15 - (swzb & 15);
  const size_t base = (size_t)bh * 2048 * 64;

  // Q B-fragments straight from global (col=q=lane&15, k=d slice)
  const int qrow = qt * 128 + w * 16 + lr;
  bf16x8 qf[2];
#pragma unroll
  for (int kk = 0; kk < 2; ++kk)
    qf[kk] = *(const bf16x8*)(qg + base + (size_t)qrow * 64 + kk * 32 + lg * 8);

  f32x4 zero = {0.f, 0.f, 0.f, 0.f};
  f32x4 accO[4];
#pragma unroll
  for (int n = 0; n < 4; ++n) accO[n] = zero;
  float mrun = -1e30f, lrun = 0.f;

  const u32* ks = (const u32*)(kg + base);
  const u32* vs = (const u32*)(vtg + base);

  // prefetch tile 0: K [key][d], V^T [d][t-slice]
  u32 kreg[4], vreg[4];
#pragma unroll
  for (int e = 0; e < 4; ++e) {
    int p = t + e * 512;
    int row = p >> 5, dp = p & 31;
    kreg[e] = ks[p];
    vreg[e] = vs[row * 1024 + dp];
  }

  const float SCL = 0.18033688011112042f;  // 0.125 * log2(e)
  const int nkt = 2 * qt + 2;

  for (int kt = 0; kt < nkt; ++kt) {
    char* kb_ = (char*)&sK[kt & 1][0];
    char* vb_ = (char*)&sVt[kt & 1][0];

    // stage current tile (conflict-free: half-wave covers a full 128B row)
#pragma unroll
    for (int e = 0; e < 4; ++e) {
      int p = t + e * 512;
      int row = p >> 5, dp = p & 31;
      int off = row * 128 + ((dp * 4) ^ ((row & 7) << 4));
      *(u32*)(kb_ + off) = kreg[e];
      *(u32*)(vb_ + off) = vreg[e];
    }

    // prefetch next tile (consumed at next iteration's staging, after barrier)
    if (kt + 1 < nkt) {
      const u32* kn = ks + (size_t)(kt + 1) * 2048;
      const u32* vn = vs + (kt + 1) * 32;
#pragma unroll
      for (int e = 0; e < 4; ++e) {
        int p = t + e * 512;
        int row = p >> 5, dp = p & 31;
        kreg[e] = kn[p];
        vreg[e] = vn[row * 1024 + dp];
      }
    }

    __syncthreads();

    // S^T = K Q^T : A = K rows (keys), B = Q cols (q = lane&15 = qrow)
    f32x4 s[4];
    __builtin_amdgcn_s_setprio(1);
#pragma unroll
    for (int n = 0; n < 4; ++n) {
      f32x4 a = zero;
#pragma unroll
      for (int kk = 0; kk < 2; ++kk) {
        bf16x8 kf = *(const bf16x8*)(kb_ + (n * 16 + lr) * 128 +
                                     ((kk * 64 + lg * 16) ^ ((lr & 7) << 4)));
        a = __builtin_amdgcn_mfma_f32_16x16x32_bf16(kf, qf[kk], a, 0, 0, 0);
      }
      s[n] = a;
    }
    __builtin_amdgcn_s_setprio(0);

    // mask + scale (exp2 domain): keys = kt*64 + n*16 + lg*4 + r
#pragma unroll
    for (int n = 0; n < 4; ++n) {
      int key0 = kt * 64 + n * 16 + lg * 4;
#pragma unroll
      for (int r = 0; r < 4; ++r) {
        float v = s[n][r] * SCL;
        s[n][r] = (key0 + r <= qrow) ? v : -1e30f;
      }
    }

    // softmax: lane-local over 16 values + 2 shfls across lg groups
    float pmax = -1e30f;
#pragma unroll
    for (int n = 0; n < 4; ++n)
      pmax = fmaxf(pmax, fmaxf(fmaxf(s[n][0], s[n][1]), fmaxf(s[n][2], s[n][3])));
    pmax = fmaxf(pmax, __shfl_xor(pmax, 16));
    pmax = fmaxf(pmax, __shfl_xor(pmax, 32));
    float mnew = fmaxf(mrun, pmax);
    float corr = exp2f(mrun - mnew);
    mrun = mnew;

    float psum = 0.f;
    u32 pk[4][2];   // packed bf16 P pairs: pk[n][h] = keys n*16+lg*4+2h, +1
#pragma unroll
    for (int n = 0; n < 4; ++n) {
      float p0 = exp2f(s[n][0] - mnew);
      float p1 = exp2f(s[n][1] - mnew);
      float p2 = exp2f(s[n][2] - mnew);
      float p3 = exp2f(s[n][3] - mnew);
      psum += (p0 + p1) + (p2 + p3);
      pk[n][0] = cvtpk(p0, p1);
      pk[n][1] = cvtpk(p2, p3);
    }
    psum += __shfl_xor(psum, 16);
    psum += __shfl_xor(psum, 32);
    lrun = lrun * corr + psum;

    // rescale accO: rows are q = lg*4+r -> fetch corr via 4 shfls
    float c4[4];
#pragma unroll
    for (int r = 0; r < 4; ++r) c4[r] = __shfl(corr, lg * 4 + r);
#pragma unroll
    for (int n = 0; n < 4; ++n)
#pragma unroll
      for (int r = 0; r < 4; ++r) accO[n][r] *= c4[r];

    // O += P V : build PV A-fragments in-register (8 shfl rounds), B = V^T
    const bool hi = (lg >> 1) & 1;
#pragma unroll
    for (int kk = 0; kk < 2; ++kk) {
      u32 g[4];
#pragma unroll
      for (int r = 0; r < 4; ++r) {
        const int rh = r >> 1, rl = r & 1;
        u32 give = ((lg & 1) ^ rh) ? pk[2 * kk + 1][rl] : pk[2 * kk][rl];
        int srcLane = ((lg & 1) * 2 + ((lg >> 1) ^ rh)) * 16 + lr;
        g[r] = (u32)__shfl((int)give, srcLane);
      }
      union { u32 u[4]; bf16x8 v; } pu;
      pu.u[0] = hi ? g[2] : g[0];
      pu.u[1] = hi ? g[3] : g[1];
      pu.u[2] = hi ? g[0] : g[2];
      pu.u[3] = hi ? g[1] : g[3];
      bf16x8 pf = pu.v;
      __builtin_amdgcn_s_setprio(1);
#pragma unroll
      for (int n = 0; n < 4; ++n) {
        bf16x8 vf = *(const bf16x8*)(vb_ + (n * 16 + lr) * 128 +
                                     ((kk * 64 + lg * 16) ^ ((lr & 7) << 4)));
        accO[n] = __builtin_amdgcn_mfma_f32_16x16x32_bf16(pf, vf, accO[n], 0, 0, 0);
      }
      __builtin_amdgcn_s_setprio(0);
    }
  }

  // epilogue: accO rows q = lg*4+r; lrun lives at lane lr==q -> 4 shfls
  const int b = bh >> 4, h = bh & 15;
#pragma unroll
  for (int r = 0; r < 4; ++r) {
    float linv = 1.f / __shfl(lrun, lg * 4 + r);
    int trow = qt * 128 + w * 16 + lg * 4 + r;
    size_t rowOff = ((size_t)b * 2048 + trow) * 1024 + h * 64;
#pragma unroll
    for (int n = 0; n < 4; ++n)
      yg[rowOff + n * 16 + lr] = f2b(accO[n][r] * linv);
  }
}

// ---- launch -----------------------------------------------------------

extern "C" void kernel_launch(void* const* d_in, const int* in_sizes, int n_in,
                              void* d_out, int out_size, void* d_ws, size_t ws_size,
                              hipStream_t stream) {
  const float* x  = (const float*)d_in[0];
  const float* Wq = (const float*)d_in[1];
  const float* bq = (const float*)d_in[2];
  const float* Wk = (const float*)d_in[3];
  const float* bk = (const float*)d_in[4];
  const float* Wv = (const float*)d_in[5];
  const float* bv = (const float*)d_in[6];
  const float* Wp = (const float*)d_in[7];
  const float* bp = (const float*)d_in[8];
  float* out = (float*)d_out;

  char* ws = (char*)d_ws;
  u16* xb  = (u16*)(ws);                      // 16 MB  [8192][1024]
  u16* wqb = (u16*)(ws + (16u << 20));        // 2 MB each
  u16* wkb = (u16*)(ws + (18u << 20));
  u16* wvb = (u16*)(ws + (20u << 20));
  u16* wpb = (u16*)(ws + (22u << 20));
  u16* qb  = (u16*)(ws + (24u << 20));        // 16 MB [bh][t][d]
  u16* kb  = (u16*)(ws + (40u << 20));        // 16 MB [bh][t][d]
  u16* vtb = (u16*)(ws + (56u << 20));        // 16 MB [bh][d][t]
  u16* yb  = (u16*)(ws + (72u << 20));        // 16 MB [8192][1024]

  // fp32 -> bf16
  cvt_bf16<<<8192, 256, 0, stream>>>(x, xb, 2097152);
  cvt_w4<<<4096, 256, 0, stream>>>(Wq, Wk, Wv, Wp, wqb, wkb, wvb, wpb);

  // QKV projections
  gemm_bt<1><<<dim3(8, 64), 256, 0, stream>>>(xb, wqb, bq, nullptr, qb, 8192, 1024, 1024);
  gemm_bt<1><<<dim3(8, 64), 256, 0, stream>>>(xb, wkb, bk, nullptr, kb, 8192, 1024, 1024);
  gemm_bt<2><<<dim3(8, 64), 256, 0, stream>>>(xb, wvb, bv, nullptr, vtb, 8192, 1024, 1024);

  // causal attention -> y bf16 [B,T,C]
  attn_fwd<<<dim3(16, 64), 512, 0, stream>>>(qb, kb, vtb, yb);

  // output projection -> fp32 d_out
  gemm_bt<0><<<dim3(8, 64), 256, 0, stream>>>(yb, wpb, bp, out, nullptr, 8192, 1024, 1024);
}

// Round 5
// 210.718 us; speedup vs baseline: 2.6511x; 1.1919x over previous
//
#include <hip/hip_runtime.h>

typedef unsigned short u16;
typedef unsigned int u32;

typedef __attribute__((ext_vector_type(4))) float f32x4;
typedef __attribute__((ext_vector_type(8))) short bf16x8;

// ---- helpers ----------------------------------------------------------

__device__ inline u16 f2b(float f) {
  union { float f; u32 u; } x; x.f = f;
  u32 u = x.u;
  u32 r = (u + 0x7fffu + ((u >> 16) & 1u)) >> 16;   // round-nearest-even
  return (u16)r;
}

__device__ inline u32 cvtpk(float lo, float hi) {
  u32 r;
  asm("v_cvt_pk_bf16_f32 %0, %1, %2" : "=v"(r) : "v"(lo), "v"(hi));
  return r;
}

__device__ inline void gload_lds16(const void* g, void* l) {
  __builtin_amdgcn_global_load_lds(
      (const __attribute__((address_space(1))) u32*)g,
      (__attribute__((address_space(3))) u32*)l, 16, 0, 0);
}

// ---- fp32 -> bf16 convert --------------------------------------------

__global__ __launch_bounds__(256) void cvt_bf16(const float* __restrict__ src,
                                                u16* __restrict__ dst, int n4) {
  int i = blockIdx.x * blockDim.x + threadIdx.x;
  if (i >= n4) return;
  float4 v = ((const float4*)src)[i];
  ushort4 o;
  o.x = f2b(v.x); o.y = f2b(v.y); o.z = f2b(v.z); o.w = f2b(v.w);
  ((ushort4*)dst)[i] = o;
}

// merged convert for the 4 weight matrices (1024 blocks each)
__global__ __launch_bounds__(256) void cvt_w4(const float* __restrict__ w0,
                                              const float* __restrict__ w1,
                                              const float* __restrict__ w2,
                                              const float* __restrict__ w3,
                                              u16* o0, u16* o1, u16* o2, u16* o3) {
  int m = blockIdx.x >> 10;
  const float* s = (m == 0) ? w0 : (m == 1) ? w1 : (m == 2) ? w2 : w3;
  u16* d = (m == 0) ? o0 : (m == 1) ? o1 : (m == 2) ? o2 : o3;
  int i = (blockIdx.x & 1023) * 256 + threadIdx.x;
  float4 v = ((const float4*)s)[i];
  ushort4 o;
  o.x = f2b(v.x); o.y = f2b(v.y); o.z = f2b(v.z); o.w = f2b(v.w);
  ((ushort4*)d)[i] = o;
}

// ---- GEMM: out[m][n] = (sum_k A[m][k] * W[n][k] + bias[n]) * oscale ---
// MODE 0: fp32 row-major [M][N] -> outF
// MODE 1: bf16 [B=4,H=16,T=2048,D=64]  (m=b*2048+t, n=h*64+d)
// MODE 2: bf16 V^T [BH=64][D=64][T=2048] (packed ushort4 along t)
// grid must be (8, 64); XCD-chunked swizzle assumes gridDim.x == 8.

template <int MODE>
__global__ __launch_bounds__(256) void gemm_bt(const u16* __restrict__ A,
                                               const u16* __restrict__ W,
                                               const float* __restrict__ bias,
                                               float* __restrict__ outF,
                                               u16* __restrict__ outB,
                                               int M, int N, int K,
                                               float oscale) {
  __shared__ u16 sA[128 * 32];
  __shared__ u16 sB[128 * 32];

  const int t = threadIdx.x;
  const int lane = t & 63;
  const int w = t >> 6;
  const int wr = w >> 1, wc = w & 1;      // 2x2 waves, each 64x64 output
  const int lr = lane & 15, lg = lane >> 4;

  // XCD-chunked swizzle: each XCD gets 8 consecutive m-panels (A-panel L2 reuse)
  int bid = blockIdx.y * 8 + blockIdx.x;
  int swz = (bid & 7) * 64 + (bid >> 3);
  const int mBase = (swz >> 3) * 128;
  const int nBase = (swz & 7) * 128;

  f32x4 zero = {0.f, 0.f, 0.f, 0.f};
  f32x4 acc[4][4];
#pragma unroll
  for (int i = 0; i < 4; ++i)
#pragma unroll
    for (int j = 0; j < 4; ++j) acc[i][j] = zero;

  const int rA = t >> 2;          // tile row covered by this thread's 16B
  const int cA = (t & 3) * 8;     // k-element offset

  for (int k0 = 0; k0 < K; k0 += 32) {
#pragma unroll
    for (int i = 0; i < 2; ++i) {
      gload_lds16(A + (size_t)(mBase + i * 64 + rA) * K + k0 + cA,
                  &sA[i * 2048 + t * 8]);
      gload_lds16(W + (size_t)(nBase + i * 64 + rA) * K + k0 + cA,
                  &sB[i * 2048 + t * 8]);
    }
    __syncthreads();

    bf16x8 af[4], bf[4];
#pragma unroll
    for (int i = 0; i < 4; ++i)
      af[i] = *(const bf16x8*)&sA[(wr * 64 + i * 16 + lr) * 32 + lg * 8];
#pragma unroll
    for (int j = 0; j < 4; ++j)
      bf[j] = *(const bf16x8*)&sB[(wc * 64 + j * 16 + lr) * 32 + lg * 8];

#pragma unroll
    for (int i = 0; i < 4; ++i)
#pragma unroll
      for (int j = 0; j < 4; ++j)
        acc[i][j] = __builtin_amdgcn_mfma_f32_16x16x32_bf16(af[i], bf[j],
                                                            acc[i][j], 0, 0, 0);
    __syncthreads();
  }

  // epilogue: C/D layout col=lane&15, row=(lane>>4)*4+r
#pragma unroll
  for (int i = 0; i < 4; ++i) {
    int row = mBase + wr * 64 + i * 16 + lg * 4;   // row % 4 == 0
#pragma unroll
    for (int j = 0; j < 4; ++j) {
      int col = nBase + wc * 64 + j * 16 + lr;
      float bv = bias[col];
      if (MODE == 2) {
        // V^T: [bh][d][t], 4 consecutive t packed
        int b = row >> 11, tp = row & 2047;
        int h = col >> 6, d = col & 63;
        ushort4 o;
        o.x = f2b((acc[i][j][0] + bv) * oscale);
        o.y = f2b((acc[i][j][1] + bv) * oscale);
        o.z = f2b((acc[i][j][2] + bv) * oscale);
        o.w = f2b((acc[i][j][3] + bv) * oscale);
        *(ushort4*)(outB + ((size_t)((b * 16 + h) * 64 + d)) * 2048 + tp) = o;
      } else {
#pragma unroll
        for (int r = 0; r < 4; ++r) {
          float v = (acc[i][j][r] + bv) * oscale;
          if (MODE == 0) {
            outF[(size_t)(row + r) * N + col] = v;
          } else {
            int m = row + r;
            int b = m >> 11, tp = m & 2047;
            int h = col >> 6, d = col & 63;
            outB[(((size_t)(b * 16 + h) * 2048) + tp) * 64 + d] = f2b(v);
          }
        }
      }
    }
  }
}

// ---- causal flash attention ------------------------------------------
// q,k: bf16 [BH=64][T=2048][D=64]; vt: bf16 [BH=64][D=64][T=2048]
// y out: bf16 [B=4][T=2048][C=1024]
// 512 thr (8 waves). Q tile = 128 rows (16/wave), KV tile = 64.
// Work-balanced: each block handles q-tiles {15-p, p} (uniform 34 KV-iters).
// Swapped QK^T (S^T = mfma(K,Q)) -> lane-local softmax (q = lane&15).
// Q pre-scaled by 0.125*log2(e) in the Q-GEMM; mask only on diagonal tiles.
// Defer-rescale (THR=8, exp2 domain). One barrier per KV tile (dbuf LDS).

__global__ __launch_bounds__(512) void attn_fwd(const u16* __restrict__ qg,
                                                const u16* __restrict__ kg,
                                                const u16* __restrict__ vtg,
                                                u16* __restrict__ yg) {
  __shared__ u16 sK[2][64 * 64];
  __shared__ u16 sVt[2][64 * 64];

  const int t = threadIdx.x;
  const int lane = t & 63;
  const int w = t >> 6;
  const int lr = lane & 15, lg = lane >> 4;

  // XCD-chunked swizzle: XCD x gets bh in [8x, 8x+8), 8 pairs each
  int bid0 = blockIdx.y * 8 + blockIdx.x;
  int swzb = (bid0 & 7) * 64 + (bid0 >> 3);
  const int bh = swzb >> 3;
  const int pair = swzb & 7;
  const size_t base = (size_t)bh * 2048 * 64;

  const u32* ks = (const u32*)(kg + base);
  const u32* vs = (const u32*)(vtg + base);

  // prefetch KV tile 0: K [key][d], V^T [d][t-slice]
  u32 kreg[4], vreg[4];
#pragma unroll
  for (int e = 0; e < 4; ++e) {
    int p = t + e * 512;
    int row = p >> 5, dp = p & 31;
    kreg[e] = ks[p];
    vreg[e] = vs[row * 1024 + dp];
  }

  f32x4 zero = {0.f, 0.f, 0.f, 0.f};
  const int b = bh >> 4, h = bh & 15;

  for (int half = 0; half < 2; ++half) {
    const int qt = half ? pair : 15 - pair;
    const int nkt = 2 * qt + 2;
    const int wq0 = qt * 128 + w * 16;
    const int qrow = wq0 + lr;

    // Q B-fragments straight from global (col=q=lane&15, k=d slice)
    bf16x8 qf[2];
#pragma unroll
    for (int kk = 0; kk < 2; ++kk)
      qf[kk] = *(const bf16x8*)(qg + base + (size_t)qrow * 64 + kk * 32 + lg * 8);

    f32x4 accO[4];
#pragma unroll
    for (int n = 0; n < 4; ++n) accO[n] = zero;
    float mrun = -1e30f, lrun = 0.f;

    for (int kt = 0; kt < nkt; ++kt) {
      char* kb_ = (char*)&sK[kt & 1][0];
      char* vb_ = (char*)&sVt[kt & 1][0];

      // stage current tile (conflict-free: half-wave covers a full 128B row)
#pragma unroll
      for (int e = 0; e < 4; ++e) {
        int p = t + e * 512;
        int row = p >> 5, dp = p & 31;
        int off = row * 128 + ((dp * 4) ^ ((row & 7) << 4));
        *(u32*)(kb_ + off) = kreg[e];
        *(u32*)(vb_ + off) = vreg[e];
      }

      // prefetch next tile (or tile 0 for the second half)
      int nextT = (kt + 1 < nkt) ? kt + 1 : (half == 0 ? 0 : -1);
      if (nextT >= 0) {
        const u32* kn = ks + (size_t)nextT * 2048;
        const u32* vn = vs + nextT * 32;
#pragma unroll
        for (int e = 0; e < 4; ++e) {
          int p = t + e * 512;
          int row = p >> 5, dp = p & 31;
          kreg[e] = kn[p];
          vreg[e] = vn[row * 1024 + dp];
        }
      }

      __syncthreads();

      // S^T = K Q^T : A = K rows (keys), B = Q cols (q = lane&15 = qrow)
      f32x4 s[4];
      __builtin_amdgcn_s_setprio(1);
#pragma unroll
      for (int n = 0; n < 4; ++n) {
        f32x4 a = zero;
#pragma unroll
        for (int kk = 0; kk < 2; ++kk) {
          bf16x8 kf = *(const bf16x8*)(kb_ + (n * 16 + lr) * 128 +
                                       ((kk * 64 + lg * 16) ^ ((lr & 7) << 4)));
          a = __builtin_amdgcn_mfma_f32_16x16x32_bf16(kf, qf[kk], a, 0, 0, 0);
        }
        s[n] = a;
      }
      __builtin_amdgcn_s_setprio(0);

      // mask only diagonal tiles (scale already folded into Q)
      if (kt * 64 + 63 > wq0) {
#pragma unroll
        for (int n = 0; n < 4; ++n) {
          int key0 = kt * 64 + n * 16 + lg * 4;
#pragma unroll
          for (int r = 0; r < 4; ++r)
            s[n][r] = (key0 + r <= qrow) ? s[n][r] : -1e30f;
        }
      }

      // softmax: lane-local over 16 values + 2 shfls across lg groups
      float pmax = -1e30f;
#pragma unroll
      for (int n = 0; n < 4; ++n)
        pmax = fmaxf(pmax, fmaxf(fmaxf(s[n][0], s[n][1]), fmaxf(s[n][2], s[n][3])));
      pmax = fmaxf(pmax, __shfl_xor(pmax, 16));
      pmax = fmaxf(pmax, __shfl_xor(pmax, 32));

      // defer-rescale: only pay the rescale when max grew materially
      const bool full = __any(pmax > mrun + 8.f);
      float mnew = full ? fmaxf(mrun, pmax) : mrun;
      float corr = full ? exp2f(mrun - mnew) : 1.f;
      mrun = mnew;

      float psum = 0.f;
      u32 pk[4][2];   // packed bf16 P pairs: pk[n][h] = keys n*16+lg*4+2h, +1
#pragma unroll
      for (int n = 0; n < 4; ++n) {
        float p0 = exp2f(s[n][0] - mnew);
        float p1 = exp2f(s[n][1] - mnew);
        float p2 = exp2f(s[n][2] - mnew);
        float p3 = exp2f(s[n][3] - mnew);
        psum += (p0 + p1) + (p2 + p3);
        pk[n][0] = cvtpk(p0, p1);
        pk[n][1] = cvtpk(p2, p3);
      }
      psum += __shfl_xor(psum, 16);
      psum += __shfl_xor(psum, 32);

      if (full) {
        lrun = lrun * corr + psum;
        float c4[4];
#pragma unroll
        for (int r = 0; r < 4; ++r) c4[r] = __shfl(corr, lg * 4 + r);
#pragma unroll
        for (int n = 0; n < 4; ++n)
#pragma unroll
          for (int r = 0; r < 4; ++r) accO[n][r] *= c4[r];
      } else {
        lrun += psum;
      }

      // O += P V : build PV A-fragments in-register (8 shfl rounds), B = V^T
      const bool hi = (lg >> 1) & 1;
#pragma unroll
      for (int kk = 0; kk < 2; ++kk) {
        u32 g[4];
#pragma unroll
        for (int r = 0; r < 4; ++r) {
          const int rh = r >> 1, rl = r & 1;
          u32 give = ((lg & 1) ^ rh) ? pk[2 * kk + 1][rl] : pk[2 * kk][rl];
          int srcLane = ((lg & 1) * 2 + ((lg >> 1) ^ rh)) * 16 + lr;
          g[r] = (u32)__shfl((int)give, srcLane);
        }
        union { u32 u[4]; bf16x8 v; } pu;
        pu.u[0] = hi ? g[2] : g[0];
        pu.u[1] = hi ? g[3] : g[1];
        pu.u[2] = hi ? g[0] : g[2];
        pu.u[3] = hi ? g[1] : g[3];
        bf16x8 pf = pu.v;
        __builtin_amdgcn_s_setprio(1);
#pragma unroll
        for (int n = 0; n < 4; ++n) {
          bf16x8 vf = *(const bf16x8*)(vb_ + (n * 16 + lr) * 128 +
                                       ((kk * 64 + lg * 16) ^ ((lr & 7) << 4)));
          accO[n] = __builtin_amdgcn_mfma_f32_16x16x32_bf16(pf, vf, accO[n], 0, 0, 0);
        }
        __builtin_amdgcn_s_setprio(0);
      }
    }

    // epilogue: accO rows q = lg*4+r; lrun lives at lane lr==q -> 4 shfls
#pragma unroll
    for (int r = 0; r < 4; ++r) {
      float linv = 1.f / __shfl(lrun, lg * 4 + r);
      int trow = qt * 128 + w * 16 + lg * 4 + r;
      size_t rowOff = ((size_t)b * 2048 + trow) * 1024 + h * 64;
#pragma unroll
      for (int n = 0; n < 4; ++n)
        yg[rowOff + n * 16 + lr] = f2b(accO[n][r] * linv);
    }
  }
}

// ---- launch -----------------------------------------------------------

extern "C" void kernel_launch(void* const* d_in, const int* in_sizes, int n_in,
                              void* d_out, int out_size, void* d_ws, size_t ws_size,
                              hipStream_t stream) {
  const float* x  = (const float*)d_in[0];
  const float* Wq = (const float*)d_in[1];
  const float* bq = (const float*)d_in[2];
  const float* Wk = (const float*)d_in[3];
  const float* bk = (const float*)d_in[4];
  const float* Wv = (const float*)d_in[5];
  const float* bv = (const float*)d_in[6];
  const float* Wp = (const float*)d_in[7];
  const float* bp = (const float*)d_in[8];
  float* out = (float*)d_out;

  char* ws = (char*)d_ws;
  u16* xb  = (u16*)(ws);                      // 16 MB  [8192][1024]
  u16* wqb = (u16*)(ws + (16u << 20));        // 2 MB each
  u16* wkb = (u16*)(ws + (18u << 20));
  u16* wvb = (u16*)(ws + (20u << 20));
  u16* wpb = (u16*)(ws + (22u << 20));
  u16* qb  = (u16*)(ws + (24u << 20));        // 16 MB [bh][t][d]
  u16* kb  = (u16*)(ws + (40u << 20));        // 16 MB [bh][t][d]
  u16* vtb = (u16*)(ws + (56u << 20));        // 16 MB [bh][d][t]
  u16* yb  = (u16*)(ws + (72u << 20));        // 16 MB [8192][1024]

  const float SCL = 0.18033688011112042f;     // 0.125 * log2(e)

  // fp32 -> bf16
  cvt_bf16<<<8192, 256, 0, stream>>>(x, xb, 2097152);
  cvt_w4<<<4096, 256, 0, stream>>>(Wq, Wk, Wv, Wp, wqb, wkb, wvb, wpb);

  // QKV projections (Q pre-scaled by SCL)
  gemm_bt<1><<<dim3(8, 64), 256, 0, stream>>>(xb, wqb, bq, nullptr, qb, 8192, 1024, 1024, SCL);
  gemm_bt<1><<<dim3(8, 64), 256, 0, stream>>>(xb, wkb, bk, nullptr, kb, 8192, 1024, 1024, 1.f);
  gemm_bt<2><<<dim3(8, 64), 256, 0, stream>>>(xb, wvb, bv, nullptr, vtb, 8192, 1024, 1024, 1.f);

  // causal attention -> y bf16 [B,T,C]
  attn_fwd<<<dim3(8, 64), 512, 0, stream>>>(qb, kb, vtb, yb);

  // output projection -> fp32 d_out
  gemm_bt<0><<<dim3(8, 64), 256, 0, stream>>>(yb, wpb, bp, out, nullptr, 8192, 1024, 1024, 1.f);
}